// Round 1
// baseline (15299.860 us; speedup 1.0000x reference)
//
#include <hip/hip_runtime.h>
#include <hip/hip_bf16.h>

// GaussianLSTM: x(4,512,256) -> 2-layer LSTM(H=256) -> stats=out@w_lin.T+b
//   sample = mu + sqrt(softplus(std))*eps ; std_full = diag-embedded std
// Outputs concat: sample (524288) | mu (524288) | std_full (134217728) f32.
//
// Strategy (round 1, correctness-first):
//   - xw = x @ w_ih^T + biases precomputed as a GEMM per layer (f32).
//   - Recurrence: 1 block/batch, 512 thr; W_hh as bf16 streamed from L2
//     (512KB/step/CU ~ 3.4us/step, the deliberate round-1 bottleneck).
//   - All scratch carved from the std_full output region (rewritten last).

#define HD 256
#define SEQ 512

__device__ inline unsigned short f2bf(float x) {
  unsigned int u = __float_as_uint(x);
  unsigned int r = (u + 0x7FFFu + ((u >> 16) & 1u)) >> 16;
  return (unsigned short)r;
}

__device__ inline void unpack2(unsigned int u, float& lo, float& hi) {
  lo = __uint_as_float(u << 16);
  hi = __uint_as_float(u & 0xFFFF0000u);
}

__device__ inline float fast_sigmoid(float z) {
  return 1.0f / (1.0f + __expf(-z));
}

__device__ inline float fast_tanh(float z) {
  // 1 - 2/(1+e^{2z}); saturates correctly for large |z|
  return 1.0f - 2.0f / (1.0f + __expf(2.0f * z));
}

// ---------------------------------------------------------------- prep: f32->bf16
__global__ __launch_bounds__(256) void prep_w(
    const float* __restrict__ w0, const float* __restrict__ w1,
    unsigned short* __restrict__ o0, unsigned short* __restrict__ o1) {
  const int i = blockIdx.x * 256 + threadIdx.x;  // 0..262143
  o0[i] = f2bf(w0[i]);
  o1[i] = f2bf(w1[i]);
}

// ------------------------------------------------- xw = in @ w^T + (ba+bb)
// in: [2048][256], w: [1024][256], xw: [2048][1024]; block = 4 rows of in.
__global__ __launch_bounds__(256) void xw_gemm(
    const float* __restrict__ xin, const float* __restrict__ w,
    const float* __restrict__ ba, const float* __restrict__ bb,
    float* __restrict__ xw) {
  __shared__ float xs[4][HD];
  const int blk = blockIdx.x, tid = threadIdx.x;
  const int row0 = blk * 4;
  for (int i = tid; i < 4 * HD; i += 256) xs[i >> 8][i & 255] = xin[(size_t)row0 * HD + i];
  __syncthreads();
  float acc[4][4];
#pragma unroll
  for (int g = 0; g < 4; ++g)
#pragma unroll
    for (int tt = 0; tt < 4; ++tt) acc[g][tt] = 0.f;
#pragma unroll 2
  for (int kc = 0; kc < 64; ++kc) {
#pragma unroll
    for (int g = 0; g < 4; ++g) {
      const int r = g * HD + tid;
      const float4 wv = ((const float4*)(w + (size_t)r * HD))[kc];
#pragma unroll
      for (int tt = 0; tt < 4; ++tt) {
        const float4 hv = ((const float4*)xs[tt])[kc];
        acc[g][tt] += wv.x * hv.x + wv.y * hv.y + wv.z * hv.z + wv.w * hv.w;
      }
    }
  }
#pragma unroll
  for (int g = 0; g < 4; ++g) {
    const int r = g * HD + tid;
    const float bias = ba[r] + bb[r];
#pragma unroll
    for (int tt = 0; tt < 4; ++tt)
      xw[(size_t)(row0 + tt) * 1024 + r] = acc[g][tt] + bias;
  }
}

// ------------------------------------------------------------- LSTM recurrence
// xw: [4][512][1024] (biases folded in), w16: [1024][256] bf16, hs: [4][512][256]
// Rows gate-major: [0,256)=i [256,512)=f [512,768)=g [768,1024)=o.
__global__ __launch_bounds__(512) void lstm_seq(
    const float* __restrict__ xw, const unsigned short* __restrict__ w16,
    float* __restrict__ hs) {
  const int b = blockIdx.x;
  const int tid = threadIdx.x;
  __shared__ __align__(16) unsigned short h2[HD];  // h as bf16
  __shared__ float gl[4][HD];                      // gate activations
  float c = 0.f;
  for (int i = tid; i < HD; i += 512) h2[i] = 0;
  __syncthreads();

  const int r0 = tid;        // i or f row
  const int r1 = tid + 512;  // g or o row
  const uint4* __restrict__ w0p = (const uint4*)(w16 + (size_t)r0 * HD);
  const uint4* __restrict__ w1p = (const uint4*)(w16 + (size_t)r1 * HD);
  const uint4* hp = (const uint4*)h2;
  const bool lo_half = (tid < HD);
  const int hd = tid & (HD - 1);

  for (int t = 0; t < SEQ; ++t) {
    const float* xwrow = xw + ((size_t)b * SEQ + t) * 1024;
    float a0 = xwrow[r0];
    float a1 = xwrow[r1];
#pragma unroll 4
    for (int kc = 0; kc < 32; ++kc) {
      const uint4 hv = hp[kc];
      const uint4 w0 = w0p[kc];
      const uint4 w1 = w1p[kc];
      float hl0, hh0, hl1, hh1, hl2, hh2, hl3, hh3, wl, wh;
      unpack2(hv.x, hl0, hh0);
      unpack2(hv.y, hl1, hh1);
      unpack2(hv.z, hl2, hh2);
      unpack2(hv.w, hl3, hh3);
      unpack2(w0.x, wl, wh); a0 += wl * hl0 + wh * hh0;
      unpack2(w0.y, wl, wh); a0 += wl * hl1 + wh * hh1;
      unpack2(w0.z, wl, wh); a0 += wl * hl2 + wh * hh2;
      unpack2(w0.w, wl, wh); a0 += wl * hl3 + wh * hh3;
      unpack2(w1.x, wl, wh); a1 += wl * hl0 + wh * hh0;
      unpack2(w1.y, wl, wh); a1 += wl * hl1 + wh * hh1;
      unpack2(w1.z, wl, wh); a1 += wl * hl2 + wh * hh2;
      unpack2(w1.w, wl, wh); a1 += wl * hl3 + wh * hh3;
    }
    const float act0 = fast_sigmoid(a0);                               // i or f
    const float act1 = lo_half ? fast_tanh(a1) : fast_sigmoid(a1);     // g or o
    gl[lo_half ? 0 : 1][hd] = act0;
    gl[lo_half ? 2 : 3][hd] = act1;
    __syncthreads();
    if (lo_half) {
      const float gi = gl[0][hd], gf = gl[1][hd], gg = gl[2][hd], go = gl[3][hd];
      c = gf * c + gi * gg;
      const float h = go * fast_tanh(c);
      hs[((size_t)b * SEQ + t) * HD + hd] = h;
      h2[hd] = f2bf(h);
    }
    __syncthreads();
  }
}

// ------------------------------------------------- head: stats = h @ w_lin^T + b
// Writes mu into its output slot; softplus(std) temporarily into sample slot.
__global__ __launch_bounds__(256) void head_stats(
    const float* __restrict__ hs1, const float* __restrict__ wlin,
    const float* __restrict__ blin, float* __restrict__ mu_out,
    float* __restrict__ sd_out) {
  __shared__ float hsm[4][HD];
  const int blk = blockIdx.x, tid = threadIdx.x;
  const int row0 = blk * 4;
  for (int i = tid; i < 4 * HD; i += 256) hsm[i >> 8][i & 255] = hs1[(size_t)row0 * HD + i];
  __syncthreads();
  const float4* wsd = (const float4*)(wlin + (size_t)tid * HD);
  const float4* wmu = (const float4*)(wlin + (size_t)(HD + tid) * HD);
  float asd[4] = {0, 0, 0, 0}, amu[4] = {0, 0, 0, 0};
#pragma unroll 4
  for (int kc = 0; kc < 64; ++kc) {
    const float4 ws = wsd[kc], wm = wmu[kc];
#pragma unroll
    for (int tt = 0; tt < 4; ++tt) {
      const float4 hv = ((const float4*)hsm[tt])[kc];
      asd[tt] += ws.x * hv.x + ws.y * hv.y + ws.z * hv.z + ws.w * hv.w;
      amu[tt] += wm.x * hv.x + wm.y * hv.y + wm.z * hv.z + wm.w * hv.w;
    }
  }
  const float bsd = blin[tid], bmu = blin[HD + tid];
#pragma unroll
  for (int tt = 0; tt < 4; ++tt) {
    const float zs = asd[tt] + bsd;
    const float sp = (zs > 15.f) ? zs : __logf(1.f + __expf(zs));  // softplus
    sd_out[(size_t)(row0 + tt) * HD + tid] = sp;
    mu_out[(size_t)(row0 + tt) * HD + tid] = amu[tt] + bmu;
  }
}

// ---------------------------------- finalize: std_full fill + sample = mu+sqrt(sd)*eps
__global__ __launch_bounds__(256) void finalize_fill(
    const float* __restrict__ eps, float* __restrict__ out) {
  float* sample = out;                 // currently holds softplus(std) temp
  float* mu = out + 524288;
  float* sf = out + 1048576;           // [2048][256][256]
  const int row = blockIdx.x;
  const int tid = threadIdx.x;
  __shared__ float sd[HD];
  sd[tid] = sample[(size_t)row * HD + tid];
  __syncthreads();
  float4* dst = (float4*)(sf + (size_t)row * HD * HD);
  const int rr = tid >> 6, m = tid & 63;
#pragma unroll 4
  for (int g = 0; g < 64; ++g) {
    const int r = g * 4 + rr;
    float4 v = make_float4(0.f, 0.f, 0.f, 0.f);
    const int base = m * 4;
    if (r >= base && r < base + 4) ((float*)&v)[r - base] = sd[r];
    dst[(size_t)r * 64 + m] = v;  // wave writes 1KB contiguous per row
  }
  const float mu_v = mu[(size_t)row * HD + tid];
  const float e = eps[(size_t)row * HD + tid];
  sample[(size_t)row * HD + tid] = mu_v + sqrtf(sd[tid]) * e;
}

extern "C" void kernel_launch(void* const* d_in, const int* in_sizes, int n_in,
                              void* d_out, int out_size, void* d_ws, size_t ws_size,
                              hipStream_t stream) {
  const float* x     = (const float*)d_in[0];
  const float* eps   = (const float*)d_in[1];
  const float* w_ih0 = (const float*)d_in[2];
  const float* w_hh0 = (const float*)d_in[3];
  const float* b_ih0 = (const float*)d_in[4];
  const float* b_hh0 = (const float*)d_in[5];
  const float* w_ih1 = (const float*)d_in[6];
  const float* w_hh1 = (const float*)d_in[7];
  const float* b_ih1 = (const float*)d_in[8];
  const float* b_hh1 = (const float*)d_in[9];
  const float* w_lin = (const float*)d_in[10];
  const float* b_lin = (const float*)d_in[11];
  float* out = (float*)d_out;

  // Scratch carved from the std_full output region (rewritten by finalize_fill).
  float* scratch = out + 1048576;
  float* xw0 = scratch;                    // 2,097,152 f32
  float* xw1 = scratch + 2097152;          // 2,097,152 f32
  float* hs0 = scratch + 4194304;          //   524,288 f32
  float* hs1 = scratch + 4718592;          //   524,288 f32
  unsigned short* whh0 = (unsigned short*)(scratch + 5242880);  // 262,144 bf16
  unsigned short* whh1 = whh0 + 262144;                         // 262,144 bf16

  hipLaunchKernelGGL(prep_w, dim3(1024), dim3(256), 0, stream, w_hh0, w_hh1, whh0, whh1);
  hipLaunchKernelGGL(xw_gemm, dim3(512), dim3(256), 0, stream, x, w_ih0, b_ih0, b_hh0, xw0);
  hipLaunchKernelGGL(lstm_seq, dim3(4), dim3(512), 0, stream, xw0, whh0, hs0);
  hipLaunchKernelGGL(xw_gemm, dim3(512), dim3(256), 0, stream, hs0, w_ih1, b_ih1, b_hh1, xw1);
  hipLaunchKernelGGL(lstm_seq, dim3(4), dim3(512), 0, stream, xw1, whh1, hs1);
  hipLaunchKernelGGL(head_stats, dim3(512), dim3(256), 0, stream, hs1, w_lin, b_lin,
                     out + 524288, out);
  hipLaunchKernelGGL(finalize_fill, dim3(2048), dim3(256), 0, stream, eps, out);
}

// Round 2
// 3288.481 us; speedup vs baseline: 4.6526x; 4.6526x over previous
//
#include <hip/hip_runtime.h>
#include <hip/hip_bf16.h>

// GaussianLSTM: x(4,512,256) -> 2-layer LSTM(H=256) -> Gaussian head.
// Outputs concat: sample (524288) | mu (524288) | std_full (134217728) f32.
//
// Round 2: persistent register-resident LSTM.
//   - 16 WGs x 1 wave per layer; each WG owns 16 hidden dims (64 W_hh rows)
//     held in VGPRs as MFMA A-fragments (bf16).
//   - Per step: one 64x256 @ 256x4 GEMM via 32x mfma_f32_16x16x32_bf16.
//   - Cross-WG per-step sync: write-once h slots + MAGIC tokens in out-scratch
//     (fully overwritten by finalize each call -> replay-safe, no stale pass).

#define HD 256
#define SEQ 512
#define MAGIC 0x7FC0BEEFu

typedef __attribute__((ext_vector_type(8))) short short8;
typedef __attribute__((ext_vector_type(4))) float f32x4;

__device__ inline unsigned short f2bf(float x) {
  unsigned int u = __float_as_uint(x);
  unsigned int r = (u + 0x7FFFu + ((u >> 16) & 1u)) >> 16;
  return (unsigned short)r;
}

__device__ inline float fast_sigmoid(float z) {
  return 1.0f / (1.0f + __expf(-z));
}

__device__ inline float fast_tanh(float z) {
  return 1.0f - 2.0f / (1.0f + __expf(2.0f * z));
}

// ------------------------------------------------- xw = in @ w^T + (ba+bb)
// in: [2048][256], w: [1024][256], xw: [2048][1024]; block = 4 rows of in.
__global__ __launch_bounds__(256) void xw_gemm(
    const float* __restrict__ xin, const float* __restrict__ w,
    const float* __restrict__ ba, const float* __restrict__ bb,
    float* __restrict__ xw) {
  __shared__ float xs[4][HD];
  const int blk = blockIdx.x, tid = threadIdx.x;
  const int row0 = blk * 4;
  for (int i = tid; i < 4 * HD; i += 256) xs[i >> 8][i & 255] = xin[(size_t)row0 * HD + i];
  __syncthreads();
  float acc[4][4];
#pragma unroll
  for (int g = 0; g < 4; ++g)
#pragma unroll
    for (int tt = 0; tt < 4; ++tt) acc[g][tt] = 0.f;
#pragma unroll 2
  for (int kc = 0; kc < 64; ++kc) {
#pragma unroll
    for (int g = 0; g < 4; ++g) {
      const int r = g * HD + tid;
      const float4 wv = ((const float4*)(w + (size_t)r * HD))[kc];
#pragma unroll
      for (int tt = 0; tt < 4; ++tt) {
        const float4 hv = ((const float4*)xs[tt])[kc];
        acc[g][tt] += wv.x * hv.x + wv.y * hv.y + wv.z * hv.z + wv.w * hv.w;
      }
    }
  }
#pragma unroll
  for (int g = 0; g < 4; ++g) {
    const int r = g * HD + tid;
    const float bias = ba[r] + bb[r];
#pragma unroll
    for (int tt = 0; tt < 4; ++tt)
      xw[(size_t)(row0 + tt) * 1024 + r] = acc[g][tt] + bias;
  }
}

// ------------------------------------------------------------- LSTM recurrence
// Persistent MFMA kernel. grid=16 WGs x 64 thr. WG g owns hidden dims
// [g*16,(g+1)*16), all 4 gates (W rows m*256 + g*16 + 0..15 for m=i,f,g,o).
// Weights as A-fragments in regs; B = h (4 batches, cols 0..3 of 16).
// h shared per-step via h16[t][4][256] bf16 + token tok[g][t] (write-once).
__global__ __launch_bounds__(64, 1) void lstm_mfma(
    const float* __restrict__ xw, const float* __restrict__ whh,
    float* __restrict__ hs, unsigned int* __restrict__ h16,
    unsigned int* __restrict__ tok) {
  const int g = blockIdx.x;    // 0..15
  const int l = threadIdx.x;   // 0..63
  const int row16 = l & 15;    // A-row within tile / C-col (batch)
  const int G = l >> 4;        // k sub-group; C rows G*4..G*4+3
  const int dim0 = g * 16 + G * 4;

  // ---- preload W_hh into MFMA A-fragments (bf16), 128 VGPRs/lane
  short8 wfrag[4][8];
#pragma unroll
  for (int m = 0; m < 4; ++m) {
#pragma unroll
    for (int kk = 0; kk < 8; ++kk) {
      const float* src = whh + ((size_t)(m * 256 + g * 16 + row16) * HD) + kk * 32 + G * 8;
      const float4 a = *(const float4*)src;
      const float4 b2 = *(const float4*)(src + 4);
      short8 wv;
      wv[0] = (short)f2bf(a.x);  wv[1] = (short)f2bf(a.y);
      wv[2] = (short)f2bf(a.z);  wv[3] = (short)f2bf(a.w);
      wv[4] = (short)f2bf(b2.x); wv[5] = (short)f2bf(b2.y);
      wv[6] = (short)f2bf(b2.z); wv[7] = (short)f2bf(b2.w);
      wfrag[m][kk] = wv;
    }
  }

  const int b = row16;                 // batch for epilogue lanes
  const bool active = (b < 4);
  const int beff = active ? b : 3;     // clamp for B-frag loads (cols 4..15 unused)
  float c0 = 0.f, c1 = 0.f, c2 = 0.f, c3 = 0.f;

  for (int t = 0; t < SEQ; ++t) {
    // xw prefetch (independent of h) — issue before the spin
    float4 xwv[4] = {};
    if (active) {
      const float* xwrow = xw + ((size_t)b * SEQ + t) * 1024 + dim0;
#pragma unroll
      for (int m = 0; m < 4; ++m) xwv[m] = *(const float4*)(xwrow + m * 256);
    }

    // wait for h(t-1), then load B fragments
    short8 bfrag[8] = {};
    if (t > 0) {
      if (l < 16) {
        const unsigned int* tp = tok + (size_t)l * SEQ + (t - 1);
        while (__hip_atomic_load(tp, __ATOMIC_ACQUIRE, __HIP_MEMORY_SCOPE_AGENT) != MAGIC) {}
      }
      const unsigned short* hb =
          (const unsigned short*)h16 + (size_t)(t - 1) * 1024 + (size_t)beff * HD + G * 8;
#pragma unroll
      for (int kk = 0; kk < 8; ++kk) bfrag[kk] = *(const short8*)(hb + kk * 32);
    }

    // z = xw + W_hh @ h
    f32x4 acc[4];
#pragma unroll
    for (int m = 0; m < 4; ++m) {
      f32x4 ai = {xwv[m].x, xwv[m].y, xwv[m].z, xwv[m].w};
      acc[m] = ai;
    }
#pragma unroll
    for (int kk = 0; kk < 8; ++kk) {
#pragma unroll
      for (int m = 0; m < 4; ++m)
        acc[m] = __builtin_amdgcn_mfma_f32_16x16x32_bf16(wfrag[m][kk], bfrag[kk], acc[m], 0, 0, 0);
    }

    // gates + state update (lane-local: all 4 gates of (dim,b) in this lane)
    if (active) {
      float h0, h1, h2, h3;
      {
        const float zi = acc[0][0], zf = acc[1][0], zg = acc[2][0], zo = acc[3][0];
        c0 = fast_sigmoid(zf) * c0 + fast_sigmoid(zi) * fast_tanh(zg);
        h0 = fast_sigmoid(zo) * fast_tanh(c0);
      }
      {
        const float zi = acc[0][1], zf = acc[1][1], zg = acc[2][1], zo = acc[3][1];
        c1 = fast_sigmoid(zf) * c1 + fast_sigmoid(zi) * fast_tanh(zg);
        h1 = fast_sigmoid(zo) * fast_tanh(c1);
      }
      {
        const float zi = acc[0][2], zf = acc[1][2], zg = acc[2][2], zo = acc[3][2];
        c2 = fast_sigmoid(zf) * c2 + fast_sigmoid(zi) * fast_tanh(zg);
        h2 = fast_sigmoid(zo) * fast_tanh(c2);
      }
      {
        const float zi = acc[0][3], zf = acc[1][3], zg = acc[2][3], zo = acc[3][3];
        c3 = fast_sigmoid(zf) * c3 + fast_sigmoid(zi) * fast_tanh(zg);
        h3 = fast_sigmoid(zo) * fast_tanh(c3);
      }
      *(float4*)(hs + ((size_t)b * SEQ + t) * HD + dim0) = make_float4(h0, h1, h2, h3);
      const unsigned int p0 = (unsigned)f2bf(h0) | ((unsigned)f2bf(h1) << 16);
      const unsigned int p1 = (unsigned)f2bf(h2) | ((unsigned)f2bf(h3) << 16);
      *(uint2*)(h16 + (size_t)t * 512 + (size_t)b * 128 + (dim0 >> 1)) = make_uint2(p0, p1);
    }
    __threadfence();  // agent-scope release of h16/hs stores
    if (l == 0)
      __hip_atomic_store(tok + (size_t)g * SEQ + t, MAGIC, __ATOMIC_RELEASE,
                         __HIP_MEMORY_SCOPE_AGENT);
  }
}

// ------------------------------------------------- head: stats = h @ w_lin^T + b
__global__ __launch_bounds__(256) void head_stats(
    const float* __restrict__ hs1, const float* __restrict__ wlin,
    const float* __restrict__ blin, float* __restrict__ mu_out,
    float* __restrict__ sd_out) {
  __shared__ float hsm[4][HD];
  const int blk = blockIdx.x, tid = threadIdx.x;
  const int row0 = blk * 4;
  for (int i = tid; i < 4 * HD; i += 256) hsm[i >> 8][i & 255] = hs1[(size_t)row0 * HD + i];
  __syncthreads();
  const float4* wsd = (const float4*)(wlin + (size_t)tid * HD);
  const float4* wmu = (const float4*)(wlin + (size_t)(HD + tid) * HD);
  float asd[4] = {0, 0, 0, 0}, amu[4] = {0, 0, 0, 0};
#pragma unroll 4
  for (int kc = 0; kc < 64; ++kc) {
    const float4 ws = wsd[kc], wm = wmu[kc];
#pragma unroll
    for (int tt = 0; tt < 4; ++tt) {
      const float4 hv = ((const float4*)hsm[tt])[kc];
      asd[tt] += ws.x * hv.x + ws.y * hv.y + ws.z * hv.z + ws.w * hv.w;
      amu[tt] += wm.x * hv.x + wm.y * hv.y + wm.z * hv.z + wm.w * hv.w;
    }
  }
  const float bsd = blin[tid], bmu = blin[HD + tid];
#pragma unroll
  for (int tt = 0; tt < 4; ++tt) {
    const float zs = asd[tt] + bsd;
    const float sp = (zs > 15.f) ? zs : __logf(1.f + __expf(zs));  // softplus
    sd_out[(size_t)(row0 + tt) * HD + tid] = sp;
    mu_out[(size_t)(row0 + tt) * HD + tid] = amu[tt] + bmu;
  }
}

// ---------------------------------- finalize: std_full fill + sample = mu+sqrt(sd)*eps
__global__ __launch_bounds__(256) void finalize_fill(
    const float* __restrict__ eps, float* __restrict__ out) {
  float* sample = out;                 // currently holds softplus(std) temp
  float* mu = out + 524288;
  float* sf = out + 1048576;           // [2048][256][256]
  const int row = blockIdx.x;
  const int tid = threadIdx.x;
  __shared__ float sd[HD];
  sd[tid] = sample[(size_t)row * HD + tid];
  __syncthreads();
  float4* dst = (float4*)(sf + (size_t)row * HD * HD);
  const int rr = tid >> 6, m = tid & 63;
#pragma unroll 4
  for (int g = 0; g < 64; ++g) {
    const int r = g * 4 + rr;
    float4 v = make_float4(0.f, 0.f, 0.f, 0.f);
    const int base = m * 4;
    if (r >= base && r < base + 4) ((float*)&v)[r - base] = sd[r];
    dst[(size_t)r * 64 + m] = v;  // wave writes 1KB contiguous per row
  }
  const float mu_v = mu[(size_t)row * HD + tid];
  const float e = eps[(size_t)row * HD + tid];
  sample[(size_t)row * HD + tid] = mu_v + sqrtf(sd[tid]) * e;
}

extern "C" void kernel_launch(void* const* d_in, const int* in_sizes, int n_in,
                              void* d_out, int out_size, void* d_ws, size_t ws_size,
                              hipStream_t stream) {
  const float* x     = (const float*)d_in[0];
  const float* eps   = (const float*)d_in[1];
  const float* w_ih0 = (const float*)d_in[2];
  const float* w_hh0 = (const float*)d_in[3];
  const float* b_ih0 = (const float*)d_in[4];
  const float* b_hh0 = (const float*)d_in[5];
  const float* w_ih1 = (const float*)d_in[6];
  const float* w_hh1 = (const float*)d_in[7];
  const float* b_ih1 = (const float*)d_in[8];
  const float* b_hh1 = (const float*)d_in[9];
  const float* w_lin = (const float*)d_in[10];
  const float* b_lin = (const float*)d_in[11];
  float* out = (float*)d_out;

  // Scratch carved from the std_full output region (fully rewritten by
  // finalize_fill each call -> tokens are never stale-MAGIC at launch).
  float* scratch = out + 1048576;
  float* xw0 = scratch;                                   // 2,097,152 f32
  float* xw1 = scratch + 2097152;                         // 2,097,152 f32
  float* hs0 = scratch + 4194304;                         //   524,288 f32
  float* hs1 = scratch + 4718592;                         //   524,288 f32
  unsigned int* h16_0 = (unsigned int*)(scratch + 5242880);  // 262,144 u32
  unsigned int* h16_1 = (unsigned int*)(scratch + 5505024);  // 262,144 u32
  unsigned int* tok0  = (unsigned int*)(scratch + 5767168);  //   8,192 u32
  unsigned int* tok1  = (unsigned int*)(scratch + 5775360);  //   8,192 u32

  hipLaunchKernelGGL(xw_gemm, dim3(512), dim3(256), 0, stream, x, w_ih0, b_ih0, b_hh0, xw0);
  hipLaunchKernelGGL(lstm_mfma, dim3(16), dim3(64), 0, stream, xw0, w_hh0, hs0, h16_0, tok0);
  hipLaunchKernelGGL(xw_gemm, dim3(512), dim3(256), 0, stream, hs0, w_ih1, b_ih1, b_hh1, xw1);
  hipLaunchKernelGGL(lstm_mfma, dim3(16), dim3(64), 0, stream, xw1, w_hh1, hs1, h16_1, tok1);
  hipLaunchKernelGGL(head_stats, dim3(512), dim3(256), 0, stream, hs1, w_lin, b_lin,
                     out + 524288, out);
  hipLaunchKernelGGL(finalize_fill, dim3(2048), dim3(256), 0, stream, eps, out);
}

// Round 3
// 1877.811 us; speedup vs baseline: 8.1477x; 1.7512x over previous
//
#include <hip/hip_runtime.h>
#include <hip/hip_bf16.h>

// GaussianLSTM: x(4,512,256) -> 2-layer LSTM(H=256) -> Gaussian head.
// Outputs concat: sample (524288) | mu (524288) | std_full (134217728) f32.
//
// Round 3: fused 2-layer persistent register-resident LSTM, fence-free sync.
//   - 32 WGs x 1 wave: WGs 0..15 = layer 0 (own 16 hidden dims each, W_hh0 in
//     VGPRs); WGs 16..31 = layer 1 (W_ih1 AND W_hh1 in VGPRs, ~380 VGPR).
//   - Layer 1 consumes layer-0 h-records directly (no xw GEMM for layer 1);
//     its recurrence hides behind layer-0's serial chain.
//   - Sync protocol (NO __threadfence -> no per-step L2 writeback):
//       publisher: 8B RELAXED/AGENT atomic stores of bf16 h record (128B)
//                  -> s_waitcnt vmcnt(0) -> RELAXED/AGENT token store
//       reader:    ACQUIRE/AGENT token spin -> RELAXED/AGENT 8B data loads
//   - All records/tokens live in out-scratch fully rewritten by finalize_fill
//     each call => tokens never stale-MAGIC at (re)launch; replay-safe.

#define HD 256
#define SEQ 512
#define MAGIC 0x7FC0BEEFu

typedef __attribute__((ext_vector_type(8))) short short8;
typedef __attribute__((ext_vector_type(4))) float f32x4;

__device__ inline unsigned short f2bf(float x) {
  unsigned int u = __float_as_uint(x);
  unsigned int r = (u + 0x7FFFu + ((u >> 16) & 1u)) >> 16;
  return (unsigned short)r;
}

__device__ inline unsigned long long pack4bf(float a, float b, float c, float d) {
  return (unsigned long long)f2bf(a) | ((unsigned long long)f2bf(b) << 16) |
         ((unsigned long long)f2bf(c) << 32) | ((unsigned long long)f2bf(d) << 48);
}

__device__ inline float fast_sigmoid(float z) {
  return 1.0f / (1.0f + __expf(-z));
}

__device__ inline float fast_tanh(float z) {
  return 1.0f - 2.0f / (1.0f + __expf(2.0f * z));
}

// Load one [1024][256] f32 weight matrix's MFMA A-fragments for WG g (rows
// m*256 + g*16 + row16, m=0..3), converting to bf16. 128 VGPRs.
__device__ inline void load_wfrag(const float* __restrict__ w, int g, int row16,
                                  int G, short8 wf[4][8]) {
#pragma unroll
  for (int m = 0; m < 4; ++m) {
#pragma unroll
    for (int kk = 0; kk < 8; ++kk) {
      const float* src = w + ((size_t)(m * 256 + g * 16 + row16) * HD) + kk * 32 + G * 8;
      const float4 a = *(const float4*)src;
      const float4 b2 = *(const float4*)(src + 4);
      short8 wv;
      wv[0] = (short)f2bf(a.x);  wv[1] = (short)f2bf(a.y);
      wv[2] = (short)f2bf(a.z);  wv[3] = (short)f2bf(a.w);
      wv[4] = (short)f2bf(b2.x); wv[5] = (short)f2bf(b2.y);
      wv[6] = (short)f2bf(b2.z); wv[7] = (short)f2bf(b2.w);
      wf[m][kk] = wv;
    }
  }
}

// Gather B-fragments (h at time tt) from publication records via agent-scope
// 8B atomic loads. Record (r,tt): 16 ulongs = [batch][16 dims] bf16.
__device__ inline void load_hfrag(const unsigned long long* __restrict__ pub,
                                  int tt, int G, int beff, short8 bf[8]) {
#pragma unroll
  for (int kk = 0; kk < 8; ++kk) {
    const int base = kk * 32 + G * 8;          // global dim base of 8-chunk
    const unsigned long long* rec =
        pub + ((size_t)(base >> 4) * SEQ + tt) * 16 + beff * 4 + ((base & 15) >> 2);
    const unsigned long long q0 =
        __hip_atomic_load(rec, __ATOMIC_RELAXED, __HIP_MEMORY_SCOPE_AGENT);
    const unsigned long long q1 =
        __hip_atomic_load(rec + 1, __ATOMIC_RELAXED, __HIP_MEMORY_SCOPE_AGENT);
    union { unsigned long long q[2]; short8 s; } u;
    u.q[0] = q0; u.q[1] = q1;
    bf[kk] = u.s;
  }
}

// ------------------------------------------------- xw = in @ w^T + (ba+bb)
__global__ __launch_bounds__(256) void xw_gemm(
    const float* __restrict__ xin, const float* __restrict__ w,
    const float* __restrict__ ba, const float* __restrict__ bb,
    float* __restrict__ xw) {
  __shared__ float xs[4][HD];
  const int blk = blockIdx.x, tid = threadIdx.x;
  const int row0 = blk * 4;
  for (int i = tid; i < 4 * HD; i += 256) xs[i >> 8][i & 255] = xin[(size_t)row0 * HD + i];
  __syncthreads();
  float acc[4][4];
#pragma unroll
  for (int g = 0; g < 4; ++g)
#pragma unroll
    for (int tt = 0; tt < 4; ++tt) acc[g][tt] = 0.f;
#pragma unroll 2
  for (int kc = 0; kc < 64; ++kc) {
#pragma unroll
    for (int g = 0; g < 4; ++g) {
      const int r = g * HD + tid;
      const float4 wv = ((const float4*)(w + (size_t)r * HD))[kc];
#pragma unroll
      for (int tt = 0; tt < 4; ++tt) {
        const float4 hv = ((const float4*)xs[tt])[kc];
        acc[g][tt] += wv.x * hv.x + wv.y * hv.y + wv.z * hv.z + wv.w * hv.w;
      }
    }
  }
#pragma unroll
  for (int g = 0; g < 4; ++g) {
    const int r = g * HD + tid;
    const float bias = ba[r] + bb[r];
#pragma unroll
    for (int tt = 0; tt < 4; ++tt)
      xw[(size_t)(row0 + tt) * 1024 + r] = acc[g][tt] + bias;
  }
}

// ------------------------------------------------------------- fused 2-layer LSTM
__global__ __launch_bounds__(64, 1) void lstm_fused(
    const float* __restrict__ xw0, const float* __restrict__ whh0,
    const float* __restrict__ wih1, const float* __restrict__ whh1,
    const float* __restrict__ bi1, const float* __restrict__ bh1,
    float* __restrict__ hs1,
    unsigned long long* __restrict__ pub0, unsigned long long* __restrict__ pub1,
    unsigned int* __restrict__ tok0, unsigned int* __restrict__ tok1) {
  const int wg = blockIdx.x;
  const int role = wg >> 4;  // 0 = layer 0, 1 = layer 1
  const int g = wg & 15;
  const int l = threadIdx.x;
  const int row16 = l & 15;  // A row within tile / C col (batch)
  const int G = l >> 4;      // k subgroup; C rows G*4..G*4+3
  const int dim0 = g * 16 + G * 4;
  const bool active = (row16 < 4);
  const int b = row16;
  const int beff = active ? b : 3;

  if (role == 0) {
    short8 wf[4][8];
    load_wfrag(whh0, g, row16, G, wf);
    float c0 = 0.f, c1 = 0.f, c2 = 0.f, c3 = 0.f;

    for (int t = 0; t < SEQ; ++t) {
      float4 xwv[4] = {};
      if (active) {
        const float* xwrow = xw0 + ((size_t)b * SEQ + t) * 1024 + dim0;
#pragma unroll
        for (int m = 0; m < 4; ++m) xwv[m] = *(const float4*)(xwrow + m * 256);
      }
      short8 bf[8] = {};
      if (t > 0) {
        if (l < 16) {
          const unsigned int* tp = tok0 + (size_t)l * SEQ + (t - 1);
          while (__hip_atomic_load(tp, __ATOMIC_ACQUIRE, __HIP_MEMORY_SCOPE_AGENT) != MAGIC) {}
        }
        load_hfrag(pub0, t - 1, G, beff, bf);
      }
      f32x4 acc[4];
#pragma unroll
      for (int m = 0; m < 4; ++m) {
        f32x4 ai = {xwv[m].x, xwv[m].y, xwv[m].z, xwv[m].w};
        acc[m] = ai;
      }
#pragma unroll
      for (int kk = 0; kk < 8; ++kk)
#pragma unroll
        for (int m = 0; m < 4; ++m)
          acc[m] = __builtin_amdgcn_mfma_f32_16x16x32_bf16(wf[m][kk], bf[kk], acc[m], 0, 0, 0);

      if (active) {
        float h0, h1, h2, h3;
        { const float zi = acc[0][0], zf = acc[1][0], zg = acc[2][0], zo = acc[3][0];
          c0 = fast_sigmoid(zf) * c0 + fast_sigmoid(zi) * fast_tanh(zg);
          h0 = fast_sigmoid(zo) * fast_tanh(c0); }
        { const float zi = acc[0][1], zf = acc[1][1], zg = acc[2][1], zo = acc[3][1];
          c1 = fast_sigmoid(zf) * c1 + fast_sigmoid(zi) * fast_tanh(zg);
          h1 = fast_sigmoid(zo) * fast_tanh(c1); }
        { const float zi = acc[0][2], zf = acc[1][2], zg = acc[2][2], zo = acc[3][2];
          c2 = fast_sigmoid(zf) * c2 + fast_sigmoid(zi) * fast_tanh(zg);
          h2 = fast_sigmoid(zo) * fast_tanh(c2); }
        { const float zi = acc[0][3], zf = acc[1][3], zg = acc[2][3], zo = acc[3][3];
          c3 = fast_sigmoid(zf) * c3 + fast_sigmoid(zi) * fast_tanh(zg);
          h3 = fast_sigmoid(zo) * fast_tanh(c3); }
        __hip_atomic_store(pub0 + ((size_t)g * SEQ + t) * 16 + b * 4 + G,
                           pack4bf(h0, h1, h2, h3), __ATOMIC_RELAXED,
                           __HIP_MEMORY_SCOPE_AGENT);
      }
      asm volatile("s_waitcnt vmcnt(0)" ::: "memory");
      if (l == 0)
        __hip_atomic_store(tok0 + (size_t)g * SEQ + t, MAGIC, __ATOMIC_RELAXED,
                           __HIP_MEMORY_SCOPE_AGENT);
    }
  } else {
    short8 wfi[4][8], wfh[4][8];
    load_wfrag(wih1, g, row16, G, wfi);
    load_wfrag(whh1, g, row16, G, wfh);
    f32x4 biasv[4];
#pragma unroll
    for (int m = 0; m < 4; ++m) {
      const float4 a = *(const float4*)(bi1 + m * 256 + dim0);
      const float4 b2 = *(const float4*)(bh1 + m * 256 + dim0);
      f32x4 bv = {a.x + b2.x, a.y + b2.y, a.z + b2.z, a.w + b2.w};
      biasv[m] = bv;
    }
    float c0 = 0.f, c1 = 0.f, c2 = 0.f, c3 = 0.f;

    for (int t = 0; t < SEQ; ++t) {
      // wait: layer-0 h(t) and own h(t-1)
      const unsigned int* tp = nullptr;
      if (l < 16) tp = tok0 + (size_t)l * SEQ + t;
      else if (l < 32 && t > 0) tp = tok1 + (size_t)(l - 16) * SEQ + (t - 1);
      if (tp)
        while (__hip_atomic_load(tp, __ATOMIC_ACQUIRE, __HIP_MEMORY_SCOPE_AGENT) != MAGIC) {}

      short8 bf0[8];
      short8 bf1[8] = {};
      load_hfrag(pub0, t, G, beff, bf0);
      if (t > 0) load_hfrag(pub1, t - 1, G, beff, bf1);

      f32x4 acc[4];
#pragma unroll
      for (int m = 0; m < 4; ++m) acc[m] = biasv[m];
#pragma unroll
      for (int kk = 0; kk < 8; ++kk)
#pragma unroll
        for (int m = 0; m < 4; ++m)
          acc[m] = __builtin_amdgcn_mfma_f32_16x16x32_bf16(wfi[m][kk], bf0[kk], acc[m], 0, 0, 0);
#pragma unroll
      for (int kk = 0; kk < 8; ++kk)
#pragma unroll
        for (int m = 0; m < 4; ++m)
          acc[m] = __builtin_amdgcn_mfma_f32_16x16x32_bf16(wfh[m][kk], bf1[kk], acc[m], 0, 0, 0);

      if (active) {
        float h0, h1, h2, h3;
        { const float zi = acc[0][0], zf = acc[1][0], zg = acc[2][0], zo = acc[3][0];
          c0 = fast_sigmoid(zf) * c0 + fast_sigmoid(zi) * fast_tanh(zg);
          h0 = fast_sigmoid(zo) * fast_tanh(c0); }
        { const float zi = acc[0][1], zf = acc[1][1], zg = acc[2][1], zo = acc[3][1];
          c1 = fast_sigmoid(zf) * c1 + fast_sigmoid(zi) * fast_tanh(zg);
          h1 = fast_sigmoid(zo) * fast_tanh(c1); }
        { const float zi = acc[0][2], zf = acc[1][2], zg = acc[2][2], zo = acc[3][2];
          c2 = fast_sigmoid(zf) * c2 + fast_sigmoid(zi) * fast_tanh(zg);
          h2 = fast_sigmoid(zo) * fast_tanh(c2); }
        { const float zi = acc[0][3], zf = acc[1][3], zg = acc[2][3], zo = acc[3][3];
          c3 = fast_sigmoid(zf) * c3 + fast_sigmoid(zi) * fast_tanh(zg);
          h3 = fast_sigmoid(zo) * fast_tanh(c3); }
        *(float4*)(hs1 + ((size_t)b * SEQ + t) * HD + dim0) = make_float4(h0, h1, h2, h3);
        __hip_atomic_store(pub1 + ((size_t)g * SEQ + t) * 16 + b * 4 + G,
                           pack4bf(h0, h1, h2, h3), __ATOMIC_RELAXED,
                           __HIP_MEMORY_SCOPE_AGENT);
      }
      asm volatile("s_waitcnt vmcnt(0)" ::: "memory");
      if (l == 0)
        __hip_atomic_store(tok1 + (size_t)g * SEQ + t, MAGIC, __ATOMIC_RELAXED,
                           __HIP_MEMORY_SCOPE_AGENT);
    }
  }
}

// ------------------------------------------------- head: stats = h @ w_lin^T + b
__global__ __launch_bounds__(256) void head_stats(
    const float* __restrict__ hs1, const float* __restrict__ wlin,
    const float* __restrict__ blin, float* __restrict__ mu_out,
    float* __restrict__ sd_out) {
  __shared__ float hsm[4][HD];
  const int blk = blockIdx.x, tid = threadIdx.x;
  const int row0 = blk * 4;
  for (int i = tid; i < 4 * HD; i += 256) hsm[i >> 8][i & 255] = hs1[(size_t)row0 * HD + i];
  __syncthreads();
  const float4* wsd = (const float4*)(wlin + (size_t)tid * HD);
  const float4* wmu = (const float4*)(wlin + (size_t)(HD + tid) * HD);
  float asd[4] = {0, 0, 0, 0}, amu[4] = {0, 0, 0, 0};
#pragma unroll 4
  for (int kc = 0; kc < 64; ++kc) {
    const float4 ws = wsd[kc], wm = wmu[kc];
#pragma unroll
    for (int tt = 0; tt < 4; ++tt) {
      const float4 hv = ((const float4*)hsm[tt])[kc];
      asd[tt] += ws.x * hv.x + ws.y * hv.y + ws.z * hv.z + ws.w * hv.w;
      amu[tt] += wm.x * hv.x + wm.y * hv.y + wm.z * hv.z + wm.w * hv.w;
    }
  }
  const float bsd = blin[tid], bmu = blin[HD + tid];
#pragma unroll
  for (int tt = 0; tt < 4; ++tt) {
    const float zs = asd[tt] + bsd;
    const float sp = (zs > 15.f) ? zs : __logf(1.f + __expf(zs));  // softplus
    sd_out[(size_t)(row0 + tt) * HD + tid] = sp;
    mu_out[(size_t)(row0 + tt) * HD + tid] = amu[tt] + bmu;
  }
}

// ---------------------------------- finalize: std_full fill + sample = mu+sqrt(sd)*eps
__global__ __launch_bounds__(256) void finalize_fill(
    const float* __restrict__ eps, float* __restrict__ out) {
  float* sample = out;                 // currently holds softplus(std) temp
  float* mu = out + 524288;
  float* sf = out + 1048576;           // [2048][256][256]
  const int row = blockIdx.x;
  const int tid = threadIdx.x;
  __shared__ float sd[HD];
  sd[tid] = sample[(size_t)row * HD + tid];
  __syncthreads();
  float4* dst = (float4*)(sf + (size_t)row * HD * HD);
  const int rr = tid >> 6, m = tid & 63;
#pragma unroll 4
  for (int g = 0; g < 64; ++g) {
    const int r = g * 4 + rr;
    float4 v = make_float4(0.f, 0.f, 0.f, 0.f);
    const int base = m * 4;
    if (r >= base && r < base + 4) ((float*)&v)[r - base] = sd[r];
    dst[(size_t)r * 64 + m] = v;
  }
  const float mu_v = mu[(size_t)row * HD + tid];
  const float e = eps[(size_t)row * HD + tid];
  sample[(size_t)row * HD + tid] = mu_v + sqrtf(sd[tid]) * e;
}

extern "C" void kernel_launch(void* const* d_in, const int* in_sizes, int n_in,
                              void* d_out, int out_size, void* d_ws, size_t ws_size,
                              hipStream_t stream) {
  const float* x     = (const float*)d_in[0];
  const float* eps   = (const float*)d_in[1];
  const float* w_ih0 = (const float*)d_in[2];
  const float* w_hh0 = (const float*)d_in[3];
  const float* b_ih0 = (const float*)d_in[4];
  const float* b_hh0 = (const float*)d_in[5];
  const float* w_ih1 = (const float*)d_in[6];
  const float* w_hh1 = (const float*)d_in[7];
  const float* b_ih1 = (const float*)d_in[8];
  const float* b_hh1 = (const float*)d_in[9];
  const float* w_lin = (const float*)d_in[10];
  const float* b_lin = (const float*)d_in[11];
  float* out = (float*)d_out;

  // Scratch carved from std_full output region (fully rewritten by finalize_fill
  // each call -> tokens never stale-MAGIC at launch; replay-safe).
  float* scratch = out + 1048576;
  float* xw0 = scratch;                                        // 2,097,152 f32
  float* hs1 = scratch + 2097152;                              //   524,288 f32
  unsigned long long* pub0 = (unsigned long long*)(scratch + 2621440);  // 1 MB
  unsigned long long* pub1 = (unsigned long long*)(scratch + 2883584);  // 1 MB
  unsigned int* tok0 = (unsigned int*)(scratch + 3145728);     // 32 KB
  unsigned int* tok1 = (unsigned int*)(scratch + 3153920);     // 32 KB

  hipLaunchKernelGGL(xw_gemm, dim3(512), dim3(256), 0, stream, x, w_ih0, b_ih0, b_hh0, xw0);
  hipLaunchKernelGGL(lstm_fused, dim3(32), dim3(64), 0, stream, xw0, w_hh0,
                     w_ih1, w_hh1, b_ih1, b_hh1, hs1, pub0, pub1, tok0, tok1);
  hipLaunchKernelGGL(head_stats, dim3(512), dim3(256), 0, stream, hs1, w_lin, b_lin,
                     out + 524288, out);
  hipLaunchKernelGGL(finalize_fill, dim3(2048), dim3(256), 0, stream, eps, out);
}